// Round 9
// baseline (321.888 us; speedup 1.0000x reference)
//
#include <hip/hip_runtime.h>
#include <stdint.h>

// out[e,o] = sum_{i,h} A[e,i,h] * W[h,i,o],  A[e] = rbf[e] @ sph[e] @ m2[e]
// Wave-ownership fused design: each WAVE owns 16 edges x all 128 outputs.
//   prolog (per wave, wave-private LDS quarter):
//     rs[e,i,k] = sum_s rbf[e,i,s] sph[e,s,k]  -> LDS bf16 (swizzled), 16 KB
//   ONE __syncthreads() (prolog->main handoff fence; once per kernel)
//   main loop over 256 chunks c=(hw=c>>6, i=c&63), K=32 per chunk:
//     lane (lr,lg) produces a[j] = sum_k rs[lr,i,k]*m2[lr,k,hw*32+lg*8+j]
//       -> that IS the MFMA A-fragment (row=lane&15, k=lg*8+j): no LDS round-trip
//     8 MFMA vs W3 chunk (chunk-major repack, 8KB contiguous, L2/L1 resident)
//   No barriers in the main loop; waves fully independent.

#define EMB 128
#define INTERM 64
#define SPH_N 16
#define KMAX 8
#define OUTD 128
#define KDIM 8192
#define NTHR 256
#define EPW 16

typedef __attribute__((ext_vector_type(8))) short bf16x8;
typedef __attribute__((ext_vector_type(4))) float f32x4;

__device__ __forceinline__ unsigned short f32_to_bf16(float f) {
  union { float f; uint32_t u; } v; v.f = f;
  uint32_t r = (v.u + 0x7fffu + ((v.u >> 16) & 1u)) >> 16;
  return (unsigned short)r;
}
__device__ __forceinline__ uint32_t cvtpk_bf16(float lo, float hi) {
  uint32_t r;
  asm("v_cvt_pk_bf16_f32 %0, %1, %2" : "=v"(r) : "v"(lo), "v"(hi));
  return r;
}
__device__ __forceinline__ float bf16lo_f(uint32_t u) { return __uint_as_float(u << 16); }
__device__ __forceinline__ float bf16hi_f(uint32_t u) { return __uint_as_float(u & 0xffff0000u); }

__global__ void k_build_inv(const int* __restrict__ id_reduce,
                            const int* __restrict__ id_ragged,
                            int* __restrict__ inv, int nTrip, int E) {
  int t = blockIdx.x * blockDim.x + threadIdx.x;
  if (t >= nTrip) return;
  int e = id_reduce[t], k = id_ragged[t];
  if (e >= 0 && e < E && k >= 0 && k < KMAX) inv[e * KMAX + k] = t;
}

// chunk-major W repack: W3[c][o][j] = bf16(W[h=(c>>6)*32+j][i=c&63][o]), c=0..255
__global__ void k_w3(const float* __restrict__ W, unsigned short* __restrict__ W3) {
  int idx = blockIdx.x * blockDim.x + threadIdx.x;  // [0, 256*128*32 = 1048576)
  int c = idx >> 12;
  int rem = idx & 4095;
  int o = rem >> 5, j = rem & 31;
  int h = ((c >> 6) << 5) + j, i = c & 63;
  W3[idx] = f32_to_bf16(W[((size_t)h * INTERM + i) * OUTD + o]);
}

__global__ __launch_bounds__(NTHR, 1) void k_fused(
    const float* __restrict__ rbf,   // [E][64][16]
    const float* __restrict__ sph,   // [E][16][8]
    const float* __restrict__ m,     // [nTrip][128]
    const int* __restrict__ inv,     // [E][8] (valid for e < E)
    const unsigned short* __restrict__ W3,  // [256][128][32]
    float* __restrict__ out, int E)
{
  __shared__ unsigned short s_rs[4][EPW * 64 * 8];  // 4 waves x 16 KB, wave-private

  int tid = threadIdx.x;
  int wid = tid >> 6, lane = tid & 63;
  int lr = lane & 15, lg = lane >> 4;
  int e0w = (blockIdx.x * 4 + wid) * EPW;
  int eg = e0w + lr;
  bool ev = (eg < E);
  unsigned short* rsb = &s_rs[wid][0];
  int esw = lr & 7;

  // ---- prolog: lane (lr,lg) computes rs[e=lr][all i][k=2lg, 2lg+1]
  {
    float sp0[16], sp1[16];
#pragma unroll
    for (int s = 0; s < 16; ++s) {
      float2 v = make_float2(0.f, 0.f);
      if (ev) v = *(const float2*)(sph + (size_t)eg * 128 + s * 8 + lg * 2);
      sp0[s] = v.x; sp1[s] = v.y;
    }
    const f32x4* rb4 = (const f32x4*)(rbf + (size_t)eg * 1024);
#pragma unroll 4
    for (int i = 0; i < 64; ++i) {
      float a0 = 0.f, a1 = 0.f;
      if (ev) {
#pragma unroll
        for (int q = 0; q < 4; ++q) {
          f32x4 r = rb4[i * 4 + q];
#pragma unroll
          for (int d = 0; d < 4; ++d) {
            a0 += r[d] * sp0[q * 4 + d];
            a1 += r[d] * sp1[q * 4 + d];
          }
        }
      }
      *(uint32_t*)&rsb[lr * 512 + ((i ^ esw) << 3) + lg * 2] = cvtpk_bf16(a0, a1);
    }
  }

  // Full fence for the LDS handoff (drains all counters + barrier; once per kernel).
  __syncthreads();

  // triplet indices for this edge, hoisted once
  int tk[8];
  if (ev) {
    int4 a = *(const int4*)(inv + (size_t)eg * 8);
    int4 b = *(const int4*)(inv + (size_t)eg * 8 + 4);
    tk[0] = a.x; tk[1] = a.y; tk[2] = a.z; tk[3] = a.w;
    tk[4] = b.x; tk[5] = b.y; tk[6] = b.z; tk[7] = b.w;
  } else {
#pragma unroll
    for (int k = 0; k < 8; ++k) tk[k] = -1;
  }

  f32x4 m2lo[8], m2hi[8];
  f32x4 acc0 = (f32x4){0.f,0.f,0.f,0.f}, acc1 = acc0, acc2 = acc0, acc3 = acc0,
        acc4 = acc0, acc5 = acc0, acc6 = acc0, acc7 = acc0;

#define PRODUCE_AF(RSV, AF)                                              \
  {                                                                      \
    float rf0 = bf16lo_f((RSV).x), rf1 = bf16hi_f((RSV).x);              \
    float rf2 = bf16lo_f((RSV).y), rf3 = bf16hi_f((RSV).y);              \
    float rf4 = bf16lo_f((RSV).z), rf5 = bf16hi_f((RSV).z);              \
    float rf6 = bf16lo_f((RSV).w), rf7 = bf16hi_f((RSV).w);              \
    f32x4 alo = rf0 * m2lo[0], ahi = rf0 * m2hi[0];                      \
    alo += rf1 * m2lo[1]; ahi += rf1 * m2hi[1];                          \
    alo += rf2 * m2lo[2]; ahi += rf2 * m2hi[2];                          \
    alo += rf3 * m2lo[3]; ahi += rf3 * m2hi[3];                          \
    alo += rf4 * m2lo[4]; ahi += rf4 * m2hi[4];                          \
    alo += rf5 * m2lo[5]; ahi += rf5 * m2hi[5];                          \
    alo += rf6 * m2lo[6]; ahi += rf6 * m2hi[6];                          \
    alo += rf7 * m2lo[7]; ahi += rf7 * m2hi[7];                          \
    union { uint4 u; bf16x8 b; } cvu;                                    \
    cvu.u.x = cvtpk_bf16(alo[0], alo[1]);                                \
    cvu.u.y = cvtpk_bf16(alo[2], alo[3]);                                \
    cvu.u.z = cvtpk_bf16(ahi[0], ahi[1]);                                \
    cvu.u.w = cvtpk_bf16(ahi[2], ahi[3]);                                \
    AF = cvu.b;                                                          \
  }

  for (int hw = 0; hw < 4; ++hw) {
    // m2 slice for this hw: lane needs m[t_k][hw*32 + lg*8 .. +7], all 8 k
#pragma unroll
    for (int k = 0; k < 8; ++k) {
      const float* mp = m + (size_t)(tk[k] < 0 ? 0 : tk[k]) * EMB + hw * 32 + lg * 8;
      f32x4 lo = *(const f32x4*)mp;
      f32x4 hi = *(const f32x4*)(mp + 4);
      bool z = tk[k] < 0;
      m2lo[k] = z ? (f32x4){0.f,0.f,0.f,0.f} : lo;
      m2hi[k] = z ? (f32x4){0.f,0.f,0.f,0.f} : hi;
    }

#pragma unroll 2
    for (int i = 0; i < 64; ++i) {
      const unsigned short* wp =
          W3 + ((size_t)(hw * 64 + i) << 12) + lr * 32 + lg * 8;
      bf16x8 bv0 = *(const bf16x8*)(wp + 0 * 512);
      bf16x8 bv1 = *(const bf16x8*)(wp + 1 * 512);
      bf16x8 bv2 = *(const bf16x8*)(wp + 2 * 512);
      bf16x8 bv3 = *(const bf16x8*)(wp + 3 * 512);
      bf16x8 bv4 = *(const bf16x8*)(wp + 4 * 512);
      bf16x8 bv5 = *(const bf16x8*)(wp + 5 * 512);
      bf16x8 bv6 = *(const bf16x8*)(wp + 6 * 512);
      bf16x8 bv7 = *(const bf16x8*)(wp + 7 * 512);
      uint4 rsv = *(const uint4*)&rsb[lr * 512 + ((i ^ esw) << 3)];
      bf16x8 af;
      PRODUCE_AF(rsv, af)
      acc0 = __builtin_amdgcn_mfma_f32_16x16x32_bf16(af, bv0, acc0, 0, 0, 0);
      acc1 = __builtin_amdgcn_mfma_f32_16x16x32_bf16(af, bv1, acc1, 0, 0, 0);
      acc2 = __builtin_amdgcn_mfma_f32_16x16x32_bf16(af, bv2, acc2, 0, 0, 0);
      acc3 = __builtin_amdgcn_mfma_f32_16x16x32_bf16(af, bv3, acc3, 0, 0, 0);
      acc4 = __builtin_amdgcn_mfma_f32_16x16x32_bf16(af, bv4, acc4, 0, 0, 0);
      acc5 = __builtin_amdgcn_mfma_f32_16x16x32_bf16(af, bv5, acc5, 0, 0, 0);
      acc6 = __builtin_amdgcn_mfma_f32_16x16x32_bf16(af, bv6, acc6, 0, 0, 0);
      acc7 = __builtin_amdgcn_mfma_f32_16x16x32_bf16(af, bv7, acc7, 0, 0, 0);
    }
  }

  // ---- epilogue: C/D layout col = lane&15 (o-within-tile), row = lg*4 + r (e-within-16)
  {
    int ebase = e0w + lg * 4;
#define STORE_T(OT, ACC)                                          \
    {                                                             \
      int o = (OT) * 16 + lr;                                     \
      _Pragma("unroll")                                           \
      for (int r = 0; r < 4; ++r) {                               \
        int e = ebase + r;                                        \
        if (e < E) out[(size_t)e * OUTD + o] = (ACC)[r];          \
      }                                                           \
    }
    STORE_T(0, acc0) STORE_T(1, acc1) STORE_T(2, acc2) STORE_T(3, acc3)
    STORE_T(4, acc4) STORE_T(5, acc5) STORE_T(6, acc6) STORE_T(7, acc7)
#undef STORE_T
  }
}

extern "C" void kernel_launch(void* const* d_in, const int* in_sizes, int n_in,
                              void* d_out, int out_size, void* d_ws, size_t ws_size,
                              hipStream_t stream) {
  const float* rbf = (const float*)d_in[0];
  const float* sph = (const float*)d_in[1];
  const float* m   = (const float*)d_in[2];
  const float* W   = (const float*)d_in[3];
  const int* id_reduce = (const int*)d_in[4];
  const int* id_ragged = (const int*)d_in[5];
  float* out = (float*)d_out;

  int E = in_sizes[0] / (INTERM * SPH_N);   // 30000
  int nTrip = in_sizes[2] / EMB;            // 240000

  char* ws = (char*)d_ws;
  int* inv = (int*)ws;                                       // [0, 1 MB)
  unsigned short* W3 = (unsigned short*)(ws + (1u << 20));   // [1, 3 MB)

  hipMemsetAsync(inv, 0xFF, (size_t)E * KMAX * sizeof(int), stream);
  k_build_inv<<<(nTrip + 255) / 256, 256, 0, stream>>>(id_reduce, id_ragged, inv, nTrip, E);
  k_w3<<<(256 * 128 * 32) / 256, 256, 0, stream>>>(W, W3);

  int nwave = (E + EPW - 1) / EPW;          // 1875
  int nblk = (nwave + 3) / 4;               // 469
  k_fused<<<nblk, NTHR, 0, stream>>>(rbf, sph, m, inv, W3, out, E);
}